// Round 15
// baseline (42.084 us; speedup 1.0000x reference)
//
#include <hip/hip_runtime.h>
#include <math.h>

#define NF    64      // filters
#define KT    402     // taps: arange(-201, 201)
#define KP    416     // padded taps = 13 * 32
#define NSTEP 13      // K-steps of 32
#define LIN   16000
#define LOUT  15599   // LIN - KT + 1
#define NB    16
#define NT    256     // output positions per block (16 subtiles x 16)
#define SPAN  672     // NT + KP data span per block
#define NCHUNK 84     // SPAN / 8 staging chunks
#define SROW  680     // A copy-row stride (elems)
#define CPAD  260     // C-tile row stride (dwords); 260 mod 32 = 4
#define TT    256     // 4 waves per block

typedef __attribute__((ext_vector_type(8))) short short8;   // 8 bf16 (4 VGPR)
typedef __attribute__((ext_vector_type(4))) float f32x4;    // MFMA acc
typedef __attribute__((ext_vector_type(4), aligned(4))) float f32x4u; // 4B-aligned store

// fp32 planes [plane][k][f] for the complex fallback path.
__device__ float g_filt[2 * KT * NF];
// B operand pre-packed in MFMA fragment order: [plane][group][s][lane][j].
// Value = bf16 split of coef(filter = 16*group + (lane&15),
//                            tap    = 8*(lane>>4) + 32*s + j).
// Each [plane][group][s] slice is 1 KB contiguous -> one gll16 per wave.
__device__ __align__(16) short g_cbf[2][4][NSTEP][64][8];

__device__ __forceinline__ short f2bf(float v) {
    unsigned u = __float_as_uint(v);
    unsigned r = (u + 0x7fffu + ((u >> 16) & 1u)) >> 16;   // RNE
    return (short)r;
}
__device__ __forceinline__ float bf2f(short s) {
    return __uint_as_float(((unsigned)(unsigned short)s) << 16);
}
// Async global->LDS 16B: per-lane global src, wave-uniform LDS base (+lane*16).
__device__ __forceinline__ void gll16(const void* g, void* l) {
    __builtin_amdgcn_global_load_lds(
        (const __attribute__((address_space(1))) void*)g,
        (__attribute__((address_space(3))) void*)l, 16, 0, 0);
}

__global__ void gabor_build_filters(const float* __restrict__ cf,
                                    const float* __restrict__ bw) {
    int idx = blockIdx.x * blockDim.x + threadIdx.x;    // f*KP + k
    if (idx >= NF * KP) return;
    int f = idx / KP;
    int k = idx - f * KP;
    float cre = 0.0f;
    if (k < KT) {
        float t = (float)(k - 201);
        float b = bw[f];
        float env = expf(-(t * t) / (2.0f * b * b)) / (sqrtf(2.0f * (float)M_PI) * b);
        float s, c;
        sincosf(cf[f] * t, &s, &c);
        cre = env * c;
        g_filt[k * NF + f]           = cre;      // re plane (fallback)
        g_filt[KT * NF + k * NF + f] = env * s;  // im plane (fallback)
    }
    short hi = f2bf(cre);
    short lo = f2bf(cre - bf2f(hi));
    int g = f >> 4;
    int s = k >> 5;
    int q = (k >> 3) & 3;
    int j = k & 7;
    int l = (f & 15) | (q << 4);
    g_cbf[0][g][s][l][j] = hi;
    g_cbf[1][g][s][l][j] = lo;
}

// MFMA implicit GEMM, real part only. T3+T4 phased K-loop with 3-deep B
// double-buffer and COUNTED vmcnt (R14 post-mortem: vmcnt(0) at phase close
// drained the same-phase stage -> ~13 phases of exposed L2 latency; counted
// vmcnt gives each stage a full phase to land -- the m218 lesson).
// Phase s: issue stage for s+2 into bb[(s+2)%3]; ds_read B from bb[s%3] + A;
// 48 MFMAs (setprio); close with vmcnt(2) (s+1's loads landed, s+2's in
// flight) + raw s_barrier + sched_barrier. Tail phases degrade to vmcnt(0).
// Buffer-reuse audit: bb[s%3] re-written at phase s+1 only after the phase-s
// barrier; readers' ds_reads completed (lgkmcnt before MFMA) before barrier.
// A (Hankel of x) via 8 shifted bf16 copies, one aligned ds_read_b128/frag.
// 3-term bf16 split (Ah*Bh + Al*Bh + Ah*Bl) emulates fp32.
__global__ __launch_bounds__(TT, 3) void gabor_conv_mfma(const float* __restrict__ x,
                                                         float* __restrict__ out,
                                                         long out_elems) {
    __shared__ __align__(16) union {
        struct {
            short h[8][SROW];          // 10,880 B
            short l[8][SROW];          // 10,880 B
            short bb[3][8][64][8];     // 24,576 B  [buf][region][lane][j]
        } k;                           // 46,336 B
        float c[32][CPAD];             // 33,280 B (half C-tile)
    } sm;

    const int tile = blockIdx.x;
    const int b    = blockIdx.y;
    const int n0   = tile * NT;
    const int tid  = threadIdx.x;
    const int wid  = tid >> 6;      // 0..3
    const int lane = tid & 63;

    // Prologue: stage B steps 0,1 (wave w -> regions w, 4+w; 1 KB each).
    gll16(&g_cbf[0][wid][0][lane][0], &sm.k.bb[0][wid][0][0]);
    gll16(&g_cbf[1][wid][0][lane][0], &sm.k.bb[0][4 + wid][0][0]);
    gll16(&g_cbf[0][wid][1][lane][0], &sm.k.bb[1][wid][0][0]);
    gll16(&g_cbf[1][wid][1][lane][0], &sm.k.bb[1][4 + wid][0][0]);

    // ---- Vectorized A staging: thread j < 84 owns x elements [8j, 8j+16),
    // builds all 8 shifted windows in registers, writes 16 ds_write_b128.
    if (tid < NCHUNK) {
        const int j  = tid;
        const int e0 = 8 * j;
        const float* __restrict__ src = x + (size_t)b * LIN + n0 + e0;

        float xv[16];
        if (n0 + e0 + 16 <= LIN) {
#pragma unroll
            for (int q = 0; q < 4; ++q) {
                float4 v = *reinterpret_cast<const float4*>(src + 4 * q);
                xv[4 * q + 0] = v.x; xv[4 * q + 1] = v.y;
                xv[4 * q + 2] = v.z; xv[4 * q + 3] = v.w;
            }
        } else {
#pragma unroll
            for (int i = 0; i < 16; ++i) {
                int gi = n0 + e0 + i;
                xv[i] = (gi < LIN) ? src[i] : 0.0f;
            }
        }

        unsigned hd[8], ld[8];   // packed bf16 pairs (low16 = even elem)
#pragma unroll
        for (int i = 0; i < 8; ++i) {
            unsigned h0 = (unsigned short)f2bf(xv[2 * i]);
            unsigned h1 = (unsigned short)f2bf(xv[2 * i + 1]);
            hd[i] = h0 | (h1 << 16);
            unsigned l0 = (unsigned short)f2bf(xv[2 * i]     - bf2f((short)h0));
            unsigned l1 = (unsigned short)f2bf(xv[2 * i + 1] - bf2f((short)h1));
            ld[i] = l0 | (l1 << 16);
        }

#pragma unroll
        for (int c = 0; c < 8; ++c) {
            unsigned wh[4], wl[4];
            if ((c & 1) == 0) {
#pragma unroll
                for (int i = 0; i < 4; ++i) {
                    wh[i] = hd[c / 2 + i];
                    wl[i] = ld[c / 2 + i];
                }
            } else {
#pragma unroll
                for (int i = 0; i < 4; ++i) {
                    int k2 = (c - 1) / 2 + i;
                    wh[i] = (hd[k2] >> 16) | (hd[k2 + 1] << 16);   // v_alignbit
                    wl[i] = (ld[k2] >> 16) | (ld[k2 + 1] << 16);
                }
            }
            uint4 vh = {wh[0], wh[1], wh[2], wh[3]};
            uint4 vl = {wl[0], wl[1], wl[2], wl[3]};
            *reinterpret_cast<uint4*>(&sm.k.h[c][e0]) = vh;
            *reinterpret_cast<uint4*>(&sm.k.l[c][e0]) = vl;
        }
    }
    __syncthreads();    // full drain: A ds_writes + B0/B1 stages landed

    // ---- Phased K-loop
    const int c8    = lane & 7;
    const int abase = 8 * ((lane >> 3) & 1) + 8 * (lane >> 4);
    const int subbase = wid * 4;    // this wave's first position-subtile
    const short* ah_base = &sm.k.h[c8][abase + 16 * subbase];
    const short* al_base = &sm.k.l[c8][abase + 16 * subbase];

    f32x4 acc[4][4];                // [n][group], all-static indexing
#pragma unroll
    for (int n = 0; n < 4; ++n)
#pragma unroll
        for (int g = 0; g < 4; ++g) {
            f32x4 z = {0.0f, 0.0f, 0.0f, 0.0f};
            acc[n][g] = z;
        }

#pragma unroll
    for (int s = 0; s < NSTEP; ++s) {
        const int cur = s % 3;
        // Issue stage for s+2 (lands during phase s+1; read at phase s+2).
        if (s + 2 < NSTEP) {
            const int nxt = (s + 2) % 3;
            gll16(&g_cbf[0][wid][s + 2][lane][0], &sm.k.bb[nxt][wid][0][0]);
            gll16(&g_cbf[1][wid][s + 2][lane][0], &sm.k.bb[nxt][4 + wid][0][0]);
        }
        // Current B from LDS (validity: previous phase's counted-vmcnt+barrier;
        // s=0,1: the prologue __syncthreads).
        short8 bh[4], bl[4];
#pragma unroll
        for (int g = 0; g < 4; ++g) {
            bh[g] = *(const short8*)(&sm.k.bb[cur][g][lane][0]);
            bl[g] = *(const short8*)(&sm.k.bb[cur][4 + g][lane][0]);
        }
        __builtin_amdgcn_s_setprio(1);
#pragma unroll
        for (int n = 0; n < 4; ++n) {
            short8 ah = *(const short8*)(ah_base + 16 * n + 32 * s);
            short8 al = *(const short8*)(al_base + 16 * n + 32 * s);
#pragma unroll
            for (int g = 0; g < 4; ++g) {
                acc[n][g] = __builtin_amdgcn_mfma_f32_16x16x32_bf16(ah, bh[g], acc[n][g], 0, 0, 0);
                acc[n][g] = __builtin_amdgcn_mfma_f32_16x16x32_bf16(al, bh[g], acc[n][g], 0, 0, 0);
                acc[n][g] = __builtin_amdgcn_mfma_f32_16x16x32_bf16(ah, bl[g], acc[n][g], 0, 0, 0);
            }
        }
        __builtin_amdgcn_s_setprio(0);
        // Phase close: counted vmcnt -- s+1's 2 loads (next phase's B) landed;
        // s+2's 2 loads stay in flight across the barrier.
        if (s + 2 < NSTEP) {
            asm volatile("s_waitcnt vmcnt(2)" ::: "memory");
        } else if (s + 1 < NSTEP) {
            asm volatile("s_waitcnt vmcnt(0)" ::: "memory");
        }
        if (s + 1 < NSTEP) {
            __builtin_amdgcn_s_barrier();
            __builtin_amdgcn_sched_barrier(0);
        }
    }

    // ---- Epilogue: two half-tile LDS-transpose passes -> coalesced stores.
    __syncthreads();    // before scatter clobbers the k-region via union

#pragma unroll
    for (int half = 0; half < 2; ++half) {
#pragma unroll
        for (int n = 0; n < 4; ++n) {
            const int colbase = 16 * (subbase + n) + 4 * (lane >> 4);
#pragma unroll
            for (int gg = 0; gg < 2; ++gg) {
                const int row = 16 * gg + (lane & 15);   // row within half-tile
                *reinterpret_cast<f32x4*>(&sm.c[row][colbase]) = acc[n][2 * half + gg];
            }
        }
        __syncthreads();

        // Stream out: one full 256-pos row per wave-instruction (1024 B).
#pragma unroll
        for (int rr = 0; rr < 8; ++rr) {
            const int rloc = 8 * wid + rr;               // 0..31
            const int f    = 32 * half + rloc;           // filter index
            const int np   = n0 + 4 * lane;
            const size_t o = (size_t)(b * NF + f) * LOUT + np;
            f32x4 v = *reinterpret_cast<const f32x4*>(&sm.c[rloc][4 * lane]);
            if (np + 3 < LOUT && (long)(o + 3) < out_elems) {
                *reinterpret_cast<f32x4u*>(out + o) = v;
            } else {
#pragma unroll
                for (int r = 0; r < 4; ++r)
                    if (np + r < LOUT && (long)(o + r) < out_elems)
                        out[o + r] = v[r];
            }
        }
        if (half == 0) __syncthreads();   // before next scatter clobbers sm.c
    }
}

// Complex fallback (folded fp32) in case d_out is interleaved complex.
__global__ __launch_bounds__(256) void gabor_conv_cplx(const float* __restrict__ x,
                                                       float* __restrict__ out,
                                                       long out_elems) {
    __shared__ float sx[256 + KT];
    const int tile = blockIdx.x, g = blockIdx.y, b = blockIdx.z;
    const int t0 = tile * 256, tid = threadIdx.x;
    const float* __restrict__ xb = x + (size_t)b * LIN;
    for (int i = tid; i < 256 + KT - 1; i += 256) {
        int idx = t0 + i;
        sx[i] = (idx < LIN) ? xb[idx] : 0.0f;
    }
    __syncthreads();
    const float* fre = g_filt + g * 16;
    const float* fim = g_filt + KT * NF + g * 16;
    float accre[16], accim[16];
    {
        float x0 = sx[tid], xm = sx[tid + 201];
        const float* c0 = fre;
        const float* cm = fre + 201 * NF;
#pragma unroll
        for (int j = 0; j < 16; ++j) accre[j] = __builtin_fmaf(xm, cm[j], x0 * c0[j]);
#pragma unroll
        for (int j = 0; j < 16; ++j) accim[j] = x0 * fim[j];
    }
#pragma unroll 2
    for (int p = 1; p <= 200; ++p) {
        float x1 = sx[tid + p], x2 = sx[tid + 402 - p];
        float xs = x1 + x2, xd = x1 - x2;
        const float* cr = fre + p * NF;
        const float* ci = fim + p * NF;
#pragma unroll
        for (int j = 0; j < 16; ++j) accre[j] = __builtin_fmaf(xs, cr[j], accre[j]);
#pragma unroll
        for (int j = 0; j < 16; ++j) accim[j] = __builtin_fmaf(xd, ci[j], accim[j]);
    }
    const int t = t0 + tid;
    if (t < LOUT) {
#pragma unroll
        for (int j = 0; j < 16; ++j) {
            size_t o = ((size_t)(b * NF + g * 16 + j) * LOUT + t) * 2;
            if ((long)(o + 1) < out_elems) {
                float2 v; v.x = accre[j]; v.y = accim[j];
                *reinterpret_cast<float2*>(out + o) = v;
            }
        }
    }
}

extern "C" void kernel_launch(void* const* d_in, const int* in_sizes, int n_in,
                              void* d_out, int out_size, void* d_ws, size_t ws_size,
                              hipStream_t stream) {
    const float* x  = (const float*)d_in[0];
    const float* cf = (const float*)d_in[1];
    const float* bw = (const float*)d_in[2];
    float* out = (float*)d_out;
    (void)d_ws; (void)ws_size;

    {
        int n = NF * KP;
        gabor_build_filters<<<(n + 255) / 256, 256, 0, stream>>>(cf, bw);
    }

    const long n_complex = (long)NB * NF * LOUT;
    const bool cplx = ((long)out_size >= 2 * n_complex);

    if (cplx) {
        dim3 grid((LOUT + 255) / 256, NF / 16, NB);
        gabor_conv_cplx<<<grid, 256, 0, stream>>>(x, out, (long)out_size);
    } else {
        dim3 grid((LOUT + NT - 1) / NT, NB);   // (61, 16)
        gabor_conv_mfma<<<grid, TT, 0, stream>>>(x, out, (long)out_size);
    }
}

// Round 16
// 33.605 us; speedup vs baseline: 1.2523x; 1.2523x over previous
//
#include <hip/hip_runtime.h>
#include <math.h>

#define NF    64      // filters
#define KT    402     // taps: arange(-201, 201)
#define KP    416     // padded taps = 13 * 32
#define NSTEP 13      // K-steps of 32
#define LIN   16000
#define LOUT  15599   // LIN - KT + 1
#define NB    16
#define NT    256     // output positions per block (16 subtiles x 16)
#define SPAN  672     // NT + KP data span per block
#define NCHUNK 84     // SPAN / 8 staging chunks
#define SROW  680     // A copy-row stride (elems)
#define CPAD  260     // C-tile row stride (dwords); 260 mod 32 = 4
#define TT    256     // 4 waves per block

typedef __attribute__((ext_vector_type(8))) _Float16 half8;  // MFMA f16 operand
typedef __attribute__((ext_vector_type(4))) float f32x4;     // MFMA acc
typedef __attribute__((ext_vector_type(4), aligned(4))) float f32x4u;

// fp32 planes [plane][k][f] for the complex fallback path.
__device__ float g_filt[2 * KT * NF];
// Single fp16 B plane, MFMA fragment order: [group][s][lane][j] =
// fp16(coef(filter = 16*group + (lane&15), tap = 8*(lane>>4) + 32*s + j)).
// Each [group][s] slice is 1 KB contiguous -> one gll16 per wave.
__device__ __align__(16) short g_cbh[4][NSTEP][64][8];

__device__ __forceinline__ short f2h(float v) {
    _Float16 h = (_Float16)v;               // v_cvt_f16_f32 (RNE)
    union { _Float16 h; short s; } u; u.h = h;
    return u.s;
}
__device__ __forceinline__ float h2f(short s) {
    union { _Float16 h; short s; } u; u.s = s;
    return (float)u.h;
}
// Async global->LDS 16B: per-lane global src, wave-uniform LDS base (+lane*16).
__device__ __forceinline__ void gll16(const void* g, void* l) {
    __builtin_amdgcn_global_load_lds(
        (const __attribute__((address_space(1))) void*)g,
        (__attribute__((address_space(3))) void*)l, 16, 0, 0);
}

__global__ void gabor_build_filters(const float* __restrict__ cf,
                                    const float* __restrict__ bw) {
    int idx = blockIdx.x * blockDim.x + threadIdx.x;    // f*KP + k
    if (idx >= NF * KP) return;
    int f = idx / KP;
    int k = idx - f * KP;
    float cre = 0.0f;
    if (k < KT) {
        float t = (float)(k - 201);
        float b = bw[f];
        float env = expf(-(t * t) / (2.0f * b * b)) / (sqrtf(2.0f * (float)M_PI) * b);
        float s, c;
        sincosf(cf[f] * t, &s, &c);
        cre = env * c;
        g_filt[k * NF + f]           = cre;      // re plane (fallback)
        g_filt[KT * NF + k * NF + f] = env * s;  // im plane (fallback)
    }
    int g = f >> 4;
    int s = k >> 5;
    int q = (k >> 3) & 3;
    int j = k & 7;
    int l = (f & 15) | (q << 4);
    g_cbh[g][s][l][j] = f2h(cre);
}

// MFMA implicit GEMM, real part only, fp16 2-term scheme:
// out = sum_k (xh + xl) * ch   (xh,xl = fp16 hi/lo split of x, 22-bit;
// ch = fp16(c), coefficient rel-err 2^-12 -> output rel-err ~2^-12, BETTER
// than the bf16 3-term's measured 2^-9; fp16 x fp16 products exact in f32).
// 2 GEMMs instead of 3 (MFMA floor 16 -> 10.6 us) and B halves to 52 KB ->
// ALL of B staged to LDS once (13 gll16/wave) -> the K-loop has NO barriers,
// NO staging: pure ds_read_b128 + MFMA, the one form hipcc schedules well
// (R14/R15 post-mortem: every phased/vmcnt variant stuck at 42-44 us;
// scheduling micro-placement exhausted -> cut work and sync instead).
// A (Hankel of x) via 8 shifted fp16 copies, one aligned ds_read_b128/frag.
__global__ __launch_bounds__(TT, 2) void gabor_conv_mfma(const float* __restrict__ x,
                                                         float* __restrict__ out,
                                                         long out_elems) {
    __shared__ __align__(16) union {
        struct {
            short h[8][SROW];              // 10,880 B  (xh shifted copies)
            short l[8][SROW];              // 10,880 B  (xl shifted copies)
            short bh[NSTEP][4][64][8];     // 53,248 B  (whole B plane)
        } k;                               // 75,008 B
        float c[32][CPAD];                 // 33,280 B (half C-tile)
    } sm;

    const int tile = blockIdx.x;
    const int b    = blockIdx.y;
    const int n0   = tile * NT;
    const int tid  = threadIdx.x;
    const int wid  = tid >> 6;      // 0..3
    const int lane = tid & 63;

    // Stage the ENTIRE B plane: wave w covers group w, all 13 steps (1KB each).
#pragma unroll
    for (int s = 0; s < NSTEP; ++s)
        gll16(&g_cbh[wid][s][lane][0], &sm.k.bh[s][wid][0][0]);

    // ---- Vectorized A staging: thread j < 84 owns x elements [8j, 8j+16),
    // builds all 8 shifted windows in registers, writes 16 ds_write_b128.
    if (tid < NCHUNK) {
        const int j  = tid;
        const int e0 = 8 * j;
        const float* __restrict__ src = x + (size_t)b * LIN + n0 + e0;

        float xv[16];
        if (n0 + e0 + 16 <= LIN) {
#pragma unroll
            for (int q = 0; q < 4; ++q) {
                float4 v = *reinterpret_cast<const float4*>(src + 4 * q);
                xv[4 * q + 0] = v.x; xv[4 * q + 1] = v.y;
                xv[4 * q + 2] = v.z; xv[4 * q + 3] = v.w;
            }
        } else {
#pragma unroll
            for (int i = 0; i < 16; ++i) {
                int gi = n0 + e0 + i;
                xv[i] = (gi < LIN) ? src[i] : 0.0f;
            }
        }

        unsigned hd[8], ld[8];   // packed fp16 pairs (low16 = even elem)
#pragma unroll
        for (int i = 0; i < 8; ++i) {
            unsigned h0 = (unsigned short)f2h(xv[2 * i]);
            unsigned h1 = (unsigned short)f2h(xv[2 * i + 1]);
            hd[i] = h0 | (h1 << 16);
            unsigned l0 = (unsigned short)f2h(xv[2 * i]     - h2f((short)h0));
            unsigned l1 = (unsigned short)f2h(xv[2 * i + 1] - h2f((short)h1));
            ld[i] = l0 | (l1 << 16);
        }

#pragma unroll
        for (int c = 0; c < 8; ++c) {
            unsigned wh[4], wl[4];
            if ((c & 1) == 0) {
#pragma unroll
                for (int i = 0; i < 4; ++i) {
                    wh[i] = hd[c / 2 + i];
                    wl[i] = ld[c / 2 + i];
                }
            } else {
#pragma unroll
                for (int i = 0; i < 4; ++i) {
                    int k2 = (c - 1) / 2 + i;
                    wh[i] = (hd[k2] >> 16) | (hd[k2 + 1] << 16);   // v_alignbit
                    wl[i] = (ld[k2] >> 16) | (ld[k2 + 1] << 16);
                }
            }
            uint4 vh = {wh[0], wh[1], wh[2], wh[3]};
            uint4 vl = {wl[0], wl[1], wl[2], wl[3]};
            *reinterpret_cast<uint4*>(&sm.k.h[c][e0]) = vh;
            *reinterpret_cast<uint4*>(&sm.k.l[c][e0]) = vl;
        }
    }
    __syncthreads();    // drains A ds_writes + all B gll16 stages

    // ---- Barrier-free K-loop
    const int c8    = lane & 7;
    const int abase = 8 * ((lane >> 3) & 1) + 8 * (lane >> 4);
    const int subbase = wid * 4;    // this wave's first position-subtile
    const short* ah_base = &sm.k.h[c8][abase + 16 * subbase];
    const short* al_base = &sm.k.l[c8][abase + 16 * subbase];

    f32x4 acc[4][4];                // [n][group], all-static indexing
#pragma unroll
    for (int n = 0; n < 4; ++n)
#pragma unroll
        for (int g = 0; g < 4; ++g) {
            f32x4 z = {0.0f, 0.0f, 0.0f, 0.0f};
            acc[n][g] = z;
        }

#pragma unroll
    for (int s = 0; s < NSTEP; ++s) {
        half8 bh[4];
#pragma unroll
        for (int g = 0; g < 4; ++g)
            bh[g] = *reinterpret_cast<const half8*>(&sm.k.bh[s][g][lane][0]);
#pragma unroll
        for (int n = 0; n < 4; ++n) {
            half8 ah = *reinterpret_cast<const half8*>(ah_base + 16 * n + 32 * s);
            half8 al = *reinterpret_cast<const half8*>(al_base + 16 * n + 32 * s);
#pragma unroll
            for (int g = 0; g < 4; ++g) {
                acc[n][g] = __builtin_amdgcn_mfma_f32_16x16x32_f16(ah, bh[g], acc[n][g], 0, 0, 0);
                acc[n][g] = __builtin_amdgcn_mfma_f32_16x16x32_f16(al, bh[g], acc[n][g], 0, 0, 0);
            }
        }
    }

    // ---- Epilogue: two half-tile LDS-transpose passes -> coalesced stores.
    __syncthreads();    // all reads of sm.k done before scatter clobbers union

#pragma unroll
    for (int half = 0; half < 2; ++half) {
#pragma unroll
        for (int n = 0; n < 4; ++n) {
            const int colbase = 16 * (subbase + n) + 4 * (lane >> 4);
#pragma unroll
            for (int gg = 0; gg < 2; ++gg) {
                const int row = 16 * gg + (lane & 15);   // row within half-tile
                *reinterpret_cast<f32x4*>(&sm.c[row][colbase]) = acc[n][2 * half + gg];
            }
        }
        __syncthreads();

        // Stream out: one full 256-pos row per wave-instruction (1024 B).
#pragma unroll
        for (int rr = 0; rr < 8; ++rr) {
            const int rloc = 8 * wid + rr;               // 0..31
            const int f    = 32 * half + rloc;           // filter index
            const int np   = n0 + 4 * lane;
            const size_t o = (size_t)(b * NF + f) * LOUT + np;
            f32x4 v = *reinterpret_cast<const f32x4*>(&sm.c[rloc][4 * lane]);
            if (np + 3 < LOUT && (long)(o + 3) < out_elems) {
                *reinterpret_cast<f32x4u*>(out + o) = v;
            } else {
#pragma unroll
                for (int r = 0; r < 4; ++r)
                    if (np + r < LOUT && (long)(o + r) < out_elems)
                        out[o + r] = v[r];
            }
        }
        if (half == 0) __syncthreads();   // before next scatter clobbers sm.c
    }
}

// Complex fallback (folded fp32) in case d_out is interleaved complex.
__global__ __launch_bounds__(256) void gabor_conv_cplx(const float* __restrict__ x,
                                                       float* __restrict__ out,
                                                       long out_elems) {
    __shared__ float sx[256 + KT];
    const int tile = blockIdx.x, g = blockIdx.y, b = blockIdx.z;
    const int t0 = tile * 256, tid = threadIdx.x;
    const float* __restrict__ xb = x + (size_t)b * LIN;
    for (int i = tid; i < 256 + KT - 1; i += 256) {
        int idx = t0 + i;
        sx[i] = (idx < LIN) ? xb[idx] : 0.0f;
    }
    __syncthreads();
    const float* fre = g_filt + g * 16;
    const float* fim = g_filt + KT * NF + g * 16;
    float accre[16], accim[16];
    {
        float x0 = sx[tid], xm = sx[tid + 201];
        const float* c0 = fre;
        const float* cm = fre + 201 * NF;
#pragma unroll
        for (int j = 0; j < 16; ++j) accre[j] = __builtin_fmaf(xm, cm[j], x0 * c0[j]);
#pragma unroll
        for (int j = 0; j < 16; ++j) accim[j] = x0 * fim[j];
    }
#pragma unroll 2
    for (int p = 1; p <= 200; ++p) {
        float x1 = sx[tid + p], x2 = sx[tid + 402 - p];
        float xs = x1 + x2, xd = x1 - x2;
        const float* cr = fre + p * NF;
        const float* ci = fim + p * NF;
#pragma unroll
        for (int j = 0; j < 16; ++j) accre[j] = __builtin_fmaf(xs, cr[j], accre[j]);
#pragma unroll
        for (int j = 0; j < 16; ++j) accim[j] = __builtin_fmaf(xd, ci[j], accim[j]);
    }
    const int t = t0 + tid;
    if (t < LOUT) {
#pragma unroll
        for (int j = 0; j < 16; ++j) {
            size_t o = ((size_t)(b * NF + g * 16 + j) * LOUT + t) * 2;
            if ((long)(o + 1) < out_elems) {
                float2 v; v.x = accre[j]; v.y = accim[j];
                *reinterpret_cast<float2*>(out + o) = v;
            }
        }
    }
}

extern "C" void kernel_launch(void* const* d_in, const int* in_sizes, int n_in,
                              void* d_out, int out_size, void* d_ws, size_t ws_size,
                              hipStream_t stream) {
    const float* x  = (const float*)d_in[0];
    const float* cf = (const float*)d_in[1];
    const float* bw = (const float*)d_in[2];
    float* out = (float*)d_out;
    (void)d_ws; (void)ws_size;

    {
        int n = NF * KP;
        gabor_build_filters<<<(n + 255) / 256, 256, 0, stream>>>(cf, bw);
    }

    const long n_complex = (long)NB * NF * LOUT;
    const bool cplx = ((long)out_size >= 2 * n_complex);

    if (cplx) {
        dim3 grid((LOUT + 255) / 256, NF / 16, NB);
        gabor_conv_cplx<<<grid, 256, 0, stream>>>(x, out, (long)out_size);
    } else {
        dim3 grid((LOUT + NT - 1) / NT, NB);   // (61, 16)
        gabor_conv_mfma<<<grid, TT, 0, stream>>>(x, out, (long)out_size);
    }
}

// Round 17
// 33.174 us; speedup vs baseline: 1.2686x; 1.0130x over previous
//
#include <hip/hip_runtime.h>
#include <math.h>

#define NF    64      // filters
#define KT    402     // taps: arange(-201, 201)
#define KP    416     // padded taps = 13 * 32
#define NSTEP 13      // K-steps of 32
#define LIN   16000
#define LOUT  15599   // LIN - KT + 1
#define NB    16
#define NT    256     // output positions per block (16 subtiles x 16)
#define SPAN  672     // NT + KP data span per block
#define NCHUNK 84     // SPAN / 8 staging chunks
#define SROW  680     // A copy-row stride (elems)
#define CPAD  260     // C-tile row stride (dwords); 260 mod 32 = 4
#define TT    256     // 4 waves per block

typedef __attribute__((ext_vector_type(8))) _Float16 half8;  // MFMA f16 operand
typedef __attribute__((ext_vector_type(4))) float f32x4;     // MFMA acc
typedef __attribute__((ext_vector_type(4), aligned(4))) float f32x4u;

// fp32 planes [plane][k][f] for the complex fallback path.
__device__ float g_filt[2 * KT * NF];
// Single fp16 B plane, MFMA fragment order: [group][s][lane][j] =
// fp16(coef(filter = 16*group + (lane&15), tap = 8*(lane>>4) + 32*s + j)).
// Each [group][s] slice is 1 KB contiguous -> one gll16 per wave.
__device__ __align__(16) short g_cbh[4][NSTEP][64][8];

__device__ __forceinline__ short f2h(float v) {
    _Float16 h = (_Float16)v;               // v_cvt_f16_f32 (RNE)
    union { _Float16 h; short s; } u; u.h = h;
    return u.s;
}
__device__ __forceinline__ float h2f(short s) {
    union { _Float16 h; short s; } u; u.s = s;
    return (float)u.h;
}
// Async global->LDS 16B: per-lane global src, wave-uniform LDS base (+lane*16).
__device__ __forceinline__ void gll16(const void* g, void* l) {
    __builtin_amdgcn_global_load_lds(
        (const __attribute__((address_space(1))) void*)g,
        (__attribute__((address_space(3))) void*)l, 16, 0, 0);
}

__global__ void gabor_build_filters(const float* __restrict__ cf,
                                    const float* __restrict__ bw) {
    int idx = blockIdx.x * blockDim.x + threadIdx.x;    // f*KP + k
    if (idx >= NF * KP) return;
    int f = idx / KP;
    int k = idx - f * KP;
    float cre = 0.0f;
    if (k < KT) {
        float t = (float)(k - 201);
        float b = bw[f];
        float env = expf(-(t * t) / (2.0f * b * b)) / (sqrtf(2.0f * (float)M_PI) * b);
        float s, c;
        sincosf(cf[f] * t, &s, &c);
        cre = env * c;
        g_filt[k * NF + f]           = cre;      // re plane (fallback)
        g_filt[KT * NF + k * NF + f] = env * s;  // im plane (fallback)
    }
    int g = f >> 4;
    int s = k >> 5;
    int q = (k >> 3) & 3;
    int j = k & 7;
    int l = (f & 15) | (q << 4);
    g_cbh[g][s][l][j] = f2h(cre);
}

// MFMA implicit GEMM, real part only, fp16 2-term (out = (xh+xl)*ch, c-err
// 2^-12-rel; products exact in f32 MFMA). Whole-B-in-LDS, barrier-free
// K-loop (R16 structure, 33.6 us: LDS pipe ~14 us was co-critical with MFMA
// ~13 us at 12 ds_read_b128/wave/step).
// R17 change: Hankel sliding-window A -- fragment(n,s) depends only on
// m = n+2s, so an 8-slot rolling register window (x2 planes, 64 VGPR) cuts
// per-step A reads 8 -> 4 (2 new m x 2 planes); total 12 -> 8 reads/step.
// Viable now because occupancy is LDS-capped at 2 blocks/CU: launch_bounds
// (TT,2) grants the full 256-VGPR budget (R7's remat failure was the
// (TT,3) ~170-VGPR cap). Slide pattern proven correct in R5.
__global__ __launch_bounds__(TT, 2) void gabor_conv_mfma(const float* __restrict__ x,
                                                         float* __restrict__ out,
                                                         long out_elems) {
    __shared__ __align__(16) union {
        struct {
            short h[8][SROW];              // 10,880 B  (xh shifted copies)
            short l[8][SROW];              // 10,880 B  (xl shifted copies)
            short bh[NSTEP][4][64][8];     // 53,248 B  (whole B plane)
        } k;                               // 75,008 B
        float c[32][CPAD];                 // 33,280 B (half C-tile)
    } sm;

    const int tile = blockIdx.x;
    const int b    = blockIdx.y;
    const int n0   = tile * NT;
    const int tid  = threadIdx.x;
    const int wid  = tid >> 6;      // 0..3
    const int lane = tid & 63;

    // Stage the ENTIRE B plane: wave w covers group w, all 13 steps (1KB each).
#pragma unroll
    for (int s = 0; s < NSTEP; ++s)
        gll16(&g_cbh[wid][s][lane][0], &sm.k.bh[s][wid][0][0]);

    // ---- Vectorized A staging: thread j < 84 owns x elements [8j, 8j+16),
    // builds all 8 shifted windows in registers, writes 16 ds_write_b128.
    if (tid < NCHUNK) {
        const int j  = tid;
        const int e0 = 8 * j;
        const float* __restrict__ src = x + (size_t)b * LIN + n0 + e0;

        float xv[16];
        if (n0 + e0 + 16 <= LIN) {
#pragma unroll
            for (int q = 0; q < 4; ++q) {
                float4 v = *reinterpret_cast<const float4*>(src + 4 * q);
                xv[4 * q + 0] = v.x; xv[4 * q + 1] = v.y;
                xv[4 * q + 2] = v.z; xv[4 * q + 3] = v.w;
            }
        } else {
#pragma unroll
            for (int i = 0; i < 16; ++i) {
                int gi = n0 + e0 + i;
                xv[i] = (gi < LIN) ? src[i] : 0.0f;
            }
        }

        unsigned hd[8], ld[8];   // packed fp16 pairs (low16 = even elem)
#pragma unroll
        for (int i = 0; i < 8; ++i) {
            unsigned h0 = (unsigned short)f2h(xv[2 * i]);
            unsigned h1 = (unsigned short)f2h(xv[2 * i + 1]);
            hd[i] = h0 | (h1 << 16);
            unsigned l0 = (unsigned short)f2h(xv[2 * i]     - h2f((short)h0));
            unsigned l1 = (unsigned short)f2h(xv[2 * i + 1] - h2f((short)h1));
            ld[i] = l0 | (l1 << 16);
        }

#pragma unroll
        for (int c = 0; c < 8; ++c) {
            unsigned wh[4], wl[4];
            if ((c & 1) == 0) {
#pragma unroll
                for (int i = 0; i < 4; ++i) {
                    wh[i] = hd[c / 2 + i];
                    wl[i] = ld[c / 2 + i];
                }
            } else {
#pragma unroll
                for (int i = 0; i < 4; ++i) {
                    int k2 = (c - 1) / 2 + i;
                    wh[i] = (hd[k2] >> 16) | (hd[k2 + 1] << 16);   // v_alignbit
                    wl[i] = (ld[k2] >> 16) | (ld[k2 + 1] << 16);
                }
            }
            uint4 vh = {wh[0], wh[1], wh[2], wh[3]};
            uint4 vl = {wl[0], wl[1], wl[2], wl[3]};
            *reinterpret_cast<uint4*>(&sm.k.h[c][e0]) = vh;
            *reinterpret_cast<uint4*>(&sm.k.l[c][e0]) = vl;
        }
    }
    __syncthreads();    // drains A ds_writes + all B gll16 stages

    // ---- Barrier-free K-loop with sliding A-window
    const int c8    = lane & 7;
    const int abase = 8 * ((lane >> 3) & 1) + 8 * (lane >> 4);
    const int subbase = wid * 4;    // this wave's first position-subtile
    const short* ah_base = &sm.k.h[c8][abase + 16 * subbase];
    const short* al_base = &sm.k.l[c8][abase + 16 * subbase];

    f32x4 acc[4][4];                // [n][group], all-static indexing
#pragma unroll
    for (int n = 0; n < 4; ++n)
#pragma unroll
        for (int g = 0; g < 4; ++g) {
            f32x4 z = {0.0f, 0.0f, 0.0f, 0.0f};
            acc[n][g] = z;
        }

    // Warm the 8-slot window (m = 0..7).
    half8 Ah[8], Al[8];
#pragma unroll
    for (int m = 0; m < 8; ++m) {
        Ah[m] = *reinterpret_cast<const half8*>(ah_base + 16 * m);
        Al[m] = *reinterpret_cast<const half8*>(al_base + 16 * m);
    }

#pragma unroll
    for (int s = 0; s < NSTEP; ++s) {
        half8 bh[4];
#pragma unroll
        for (int g = 0; g < 4; ++g)
            bh[g] = *reinterpret_cast<const half8*>(&sm.k.bh[s][g][lane][0]);
#pragma unroll
        for (int n = 0; n < 4; ++n) {
            const int slot = (2 * s + n) & 7;    // m = n + 2s, compile-time
#pragma unroll
            for (int g = 0; g < 4; ++g) {
                acc[n][g] = __builtin_amdgcn_mfma_f32_16x16x32_f16(Ah[slot], bh[g], acc[n][g], 0, 0, 0);
                acc[n][g] = __builtin_amdgcn_mfma_f32_16x16x32_f16(Al[slot], bh[g], acc[n][g], 0, 0, 0);
            }
        }
        if (s + 1 < NSTEP) {    // slide: refill slots for m = 2s+8, 2s+9
            const int m0 = 2 * s + 8, m1 = 2 * s + 9;
            Ah[m0 & 7] = *reinterpret_cast<const half8*>(ah_base + 16 * m0);
            Al[m0 & 7] = *reinterpret_cast<const half8*>(al_base + 16 * m0);
            Ah[m1 & 7] = *reinterpret_cast<const half8*>(ah_base + 16 * m1);
            Al[m1 & 7] = *reinterpret_cast<const half8*>(al_base + 16 * m1);
        }
    }

    // ---- Epilogue: two half-tile LDS-transpose passes -> coalesced stores.
    __syncthreads();    // all reads of sm.k done before scatter clobbers union

#pragma unroll
    for (int half = 0; half < 2; ++half) {
#pragma unroll
        for (int n = 0; n < 4; ++n) {
            const int colbase = 16 * (subbase + n) + 4 * (lane >> 4);
#pragma unroll
            for (int gg = 0; gg < 2; ++gg) {
                const int row = 16 * gg + (lane & 15);   // row within half-tile
                *reinterpret_cast<f32x4*>(&sm.c[row][colbase]) = acc[n][2 * half + gg];
            }
        }
        __syncthreads();

        // Stream out: one full 256-pos row per wave-instruction (1024 B).
#pragma unroll
        for (int rr = 0; rr < 8; ++rr) {
            const int rloc = 8 * wid + rr;               // 0..31
            const int f    = 32 * half + rloc;           // filter index
            const int np   = n0 + 4 * lane;
            const size_t o = (size_t)(b * NF + f) * LOUT + np;
            f32x4 v = *reinterpret_cast<const f32x4*>(&sm.c[rloc][4 * lane]);
            if (np + 3 < LOUT && (long)(o + 3) < out_elems) {
                *reinterpret_cast<f32x4u*>(out + o) = v;
            } else {
#pragma unroll
                for (int r = 0; r < 4; ++r)
                    if (np + r < LOUT && (long)(o + r) < out_elems)
                        out[o + r] = v[r];
            }
        }
        if (half == 0) __syncthreads();   // before next scatter clobbers sm.c
    }
}

// Complex fallback (folded fp32) in case d_out is interleaved complex.
__global__ __launch_bounds__(256) void gabor_conv_cplx(const float* __restrict__ x,
                                                       float* __restrict__ out,
                                                       long out_elems) {
    __shared__ float sx[256 + KT];
    const int tile = blockIdx.x, g = blockIdx.y, b = blockIdx.z;
    const int t0 = tile * 256, tid = threadIdx.x;
    const float* __restrict__ xb = x + (size_t)b * LIN;
    for (int i = tid; i < 256 + KT - 1; i += 256) {
        int idx = t0 + i;
        sx[i] = (idx < LIN) ? xb[idx] : 0.0f;
    }
    __syncthreads();
    const float* fre = g_filt + g * 16;
    const float* fim = g_filt + KT * NF + g * 16;
    float accre[16], accim[16];
    {
        float x0 = sx[tid], xm = sx[tid + 201];
        const float* c0 = fre;
        const float* cm = fre + 201 * NF;
#pragma unroll
        for (int j = 0; j < 16; ++j) accre[j] = __builtin_fmaf(xm, cm[j], x0 * c0[j]);
#pragma unroll
        for (int j = 0; j < 16; ++j) accim[j] = x0 * fim[j];
    }
#pragma unroll 2
    for (int p = 1; p <= 200; ++p) {
        float x1 = sx[tid + p], x2 = sx[tid + 402 - p];
        float xs = x1 + x2, xd = x1 - x2;
        const float* cr = fre + p * NF;
        const float* ci = fim + p * NF;
#pragma unroll
        for (int j = 0; j < 16; ++j) accre[j] = __builtin_fmaf(xs, cr[j], accre[j]);
#pragma unroll
        for (int j = 0; j < 16; ++j) accim[j] = __builtin_fmaf(xd, ci[j], accim[j]);
    }
    const int t = t0 + tid;
    if (t < LOUT) {
#pragma unroll
        for (int j = 0; j < 16; ++j) {
            size_t o = ((size_t)(b * NF + g * 16 + j) * LOUT + t) * 2;
            if ((long)(o + 1) < out_elems) {
                float2 v; v.x = accre[j]; v.y = accim[j];
                *reinterpret_cast<float2*>(out + o) = v;
            }
        }
    }
}

extern "C" void kernel_launch(void* const* d_in, const int* in_sizes, int n_in,
                              void* d_out, int out_size, void* d_ws, size_t ws_size,
                              hipStream_t stream) {
    const float* x  = (const float*)d_in[0];
    const float* cf = (const float*)d_in[1];
    const float* bw = (const float*)d_in[2];
    float* out = (float*)d_out;
    (void)d_ws; (void)ws_size;

    {
        int n = NF * KP;
        gabor_build_filters<<<(n + 255) / 256, 256, 0, stream>>>(cf, bw);
    }

    const long n_complex = (long)NB * NF * LOUT;
    const bool cplx = ((long)out_size >= 2 * n_complex);

    if (cplx) {
        dim3 grid((LOUT + 255) / 256, NF / 16, NB);
        gabor_conv_cplx<<<grid, 256, 0, stream>>>(x, out, (long)out_size);
    } else {
        dim3 grid((LOUT + NT - 1) / NT, NB);   // (61, 16)
        gabor_conv_mfma<<<grid, TT, 0, stream>>>(x, out, (long)out_size);
    }
}

// Round 18
// 27.373 us; speedup vs baseline: 1.5374x; 1.2119x over previous
//
#include <hip/hip_runtime.h>
#include <math.h>

#define NF    64      // filters
#define KT    402     // taps: arange(-201, 201)
#define KP    416     // padded taps = 13 * 32
#define NSTEP 13      // K-steps of 32
#define LIN   16000
#define LOUT  15599   // LIN - KT + 1
#define NB    16
#define NT    256     // output positions per block (16 subtiles x 16)
#define SPAN  672     // NT + KP data span per block
#define NCHUNK 84     // SPAN / 8 staging chunks
#define SROW  680     // A copy-row stride (elems)
#define CPAD  260     // C-tile row stride (dwords); 260 mod 32 = 4
#define TT    256     // 4 waves per block

typedef __attribute__((ext_vector_type(8))) _Float16 half8;  // MFMA f16 operand
typedef __attribute__((ext_vector_type(4))) float f32x4;     // MFMA acc
typedef __attribute__((ext_vector_type(4), aligned(4))) float f32x4u;

// fp32 planes [plane][k][f] for the complex fallback path.
__device__ float g_filt[2 * KT * NF];
// Single fp16 B plane, MFMA fragment order: [group][s][lane][j] =
// fp16(coef(filter = 16*group + (lane&15), tap = 8*(lane>>4) + 32*s + j)).
// Each [group][s] slice is 1 KB contiguous -> one gll16 per wave.
__device__ __align__(16) short g_cbh[4][NSTEP][64][8];

__device__ __forceinline__ short f2h(float v) {
    _Float16 h = (_Float16)v;               // v_cvt_f16_f32 (RNE)
    union { _Float16 h; short s; } u; u.h = h;
    return u.s;
}
// Async global->LDS 16B: per-lane global src, wave-uniform LDS base (+lane*16).
__device__ __forceinline__ void gll16(const void* g, void* l) {
    __builtin_amdgcn_global_load_lds(
        (const __attribute__((address_space(1))) void*)g,
        (__attribute__((address_space(3))) void*)l, 16, 0, 0);
}

__global__ void gabor_build_filters(const float* __restrict__ cf,
                                    const float* __restrict__ bw) {
    int idx = blockIdx.x * blockDim.x + threadIdx.x;    // f*KP + k
    if (idx >= NF * KP) return;
    int f = idx / KP;
    int k = idx - f * KP;
    float cre = 0.0f;
    if (k < KT) {
        float t = (float)(k - 201);
        float b = bw[f];
        float env = expf(-(t * t) / (2.0f * b * b)) / (sqrtf(2.0f * (float)M_PI) * b);
        float s, c;
        sincosf(cf[f] * t, &s, &c);
        cre = env * c;
        g_filt[k * NF + f]           = cre;      // re plane (fallback)
        g_filt[KT * NF + k * NF + f] = env * s;  // im plane (fallback)
    }
    int g = f >> 4;
    int s = k >> 5;
    int q = (k >> 3) & 3;
    int j = k & 7;
    int l = (f & 15) | (q << 4);
    g_cbh[g][s][l][j] = f2h(cre);
}

// MFMA implicit GEMM, real part only, fp16 1-TERM scheme: out = xh * ch.
// R18 rationale: absmax was EXACTLY 0.001953125 across bf16-3term AND
// fp16-2term -> the error is dominated by a shared source (filter-build fp32
// ULP diffs vs the jax reference), not by our quantization. Dropping the xl
// plane adds only ~1.5e-4 max error (2^-12 rel on x, 402-term RMS) while
// HALVING MFMA work (floor 12.8 -> 6.4 us), halving A-LDS traffic, and
// shrinking LDS 75 -> 64 KB. HBM write (10.2 us) becomes the dominant floor.
// Whole-B-in-LDS, barrier-free K-loop (R16 structure); sliding A-window
// kept (correct either way; guarded refills).
__global__ __launch_bounds__(TT, 2) void gabor_conv_mfma(const float* __restrict__ x,
                                                         float* __restrict__ out,
                                                         long out_elems) {
    __shared__ __align__(16) union {
        struct {
            short h[8][SROW];              // 10,880 B  (xh shifted copies)
            short bh[NSTEP][4][64][8];     // 53,248 B  (whole B plane)
        } k;                               // 64,128 B
        float c[32][CPAD];                 // 33,280 B (half C-tile)
    } sm;

    const int tile = blockIdx.x;
    const int b    = blockIdx.y;
    const int n0   = tile * NT;
    const int tid  = threadIdx.x;
    const int wid  = tid >> 6;      // 0..3
    const int lane = tid & 63;

    // Stage the ENTIRE B plane: wave w covers group w, all 13 steps (1KB each).
#pragma unroll
    for (int s = 0; s < NSTEP; ++s)
        gll16(&g_cbh[wid][s][lane][0], &sm.k.bh[s][wid][0][0]);

    // ---- Vectorized A staging: thread j < 84 owns x elements [8j, 8j+16),
    // builds all 8 shifted fp16 windows in registers, writes 8 ds_write_b128.
    if (tid < NCHUNK) {
        const int j  = tid;
        const int e0 = 8 * j;
        const float* __restrict__ src = x + (size_t)b * LIN + n0 + e0;

        float xv[16];
        if (n0 + e0 + 16 <= LIN) {
#pragma unroll
            for (int q = 0; q < 4; ++q) {
                float4 v = *reinterpret_cast<const float4*>(src + 4 * q);
                xv[4 * q + 0] = v.x; xv[4 * q + 1] = v.y;
                xv[4 * q + 2] = v.z; xv[4 * q + 3] = v.w;
            }
        } else {
#pragma unroll
            for (int i = 0; i < 16; ++i) {
                int gi = n0 + e0 + i;
                xv[i] = (gi < LIN) ? src[i] : 0.0f;
            }
        }

        unsigned hd[8];          // packed fp16 pairs (low16 = even elem)
#pragma unroll
        for (int i = 0; i < 8; ++i) {
            unsigned h0 = (unsigned short)f2h(xv[2 * i]);
            unsigned h1 = (unsigned short)f2h(xv[2 * i + 1]);
            hd[i] = h0 | (h1 << 16);
        }

#pragma unroll
        for (int c = 0; c < 8; ++c) {
            unsigned wh[4];
            if ((c & 1) == 0) {
#pragma unroll
                for (int i = 0; i < 4; ++i) wh[i] = hd[c / 2 + i];
            } else {
#pragma unroll
                for (int i = 0; i < 4; ++i) {
                    int k2 = (c - 1) / 2 + i;
                    wh[i] = (hd[k2] >> 16) | (hd[k2 + 1] << 16);   // v_alignbit
                }
            }
            uint4 vh = {wh[0], wh[1], wh[2], wh[3]};
            *reinterpret_cast<uint4*>(&sm.k.h[c][e0]) = vh;
        }
    }
    __syncthreads();    // drains A ds_writes + all B gll16 stages

    // ---- Barrier-free K-loop with sliding A-window
    const int c8    = lane & 7;
    const int abase = 8 * ((lane >> 3) & 1) + 8 * (lane >> 4);
    const int subbase = wid * 4;    // this wave's first position-subtile
    const short* ah_base = &sm.k.h[c8][abase + 16 * subbase];

    f32x4 acc[4][4];                // [n][group], all-static indexing
#pragma unroll
    for (int n = 0; n < 4; ++n)
#pragma unroll
        for (int g = 0; g < 4; ++g) {
            f32x4 z = {0.0f, 0.0f, 0.0f, 0.0f};
            acc[n][g] = z;
        }

    // Warm the 8-slot window (m = 0..7); m = n + 2s ranges 0..27.
    half8 Ah[8];
#pragma unroll
    for (int m = 0; m < 8; ++m)
        Ah[m] = *reinterpret_cast<const half8*>(ah_base + 16 * m);

#pragma unroll
    for (int s = 0; s < NSTEP; ++s) {
        half8 bh[4];
#pragma unroll
        for (int g = 0; g < 4; ++g)
            bh[g] = *reinterpret_cast<const half8*>(&sm.k.bh[s][g][lane][0]);
#pragma unroll
        for (int n = 0; n < 4; ++n) {
            const int slot = (2 * s + n) & 7;    // m = n + 2s, compile-time
#pragma unroll
            for (int g = 0; g < 4; ++g)
                acc[n][g] = __builtin_amdgcn_mfma_f32_16x16x32_f16(Ah[slot], bh[g], acc[n][g], 0, 0, 0);
        }
        if (s + 1 < NSTEP) {    // slide: refill slots for m = 2s+8, 2s+9 (<= 27)
            const int m0 = 2 * s + 8, m1 = 2 * s + 9;
            if (m0 < 28) Ah[m0 & 7] = *reinterpret_cast<const half8*>(ah_base + 16 * m0);
            if (m1 < 28) Ah[m1 & 7] = *reinterpret_cast<const half8*>(ah_base + 16 * m1);
        }
    }

    // ---- Epilogue: two half-tile LDS-transpose passes -> coalesced stores.
    __syncthreads();    // all reads of sm.k done before scatter clobbers union

#pragma unroll
    for (int half = 0; half < 2; ++half) {
#pragma unroll
        for (int n = 0; n < 4; ++n) {
            const int colbase = 16 * (subbase + n) + 4 * (lane >> 4);
#pragma unroll
            for (int gg = 0; gg < 2; ++gg) {
                const int row = 16 * gg + (lane & 15);   // row within half-tile
                *reinterpret_cast<f32x4*>(&sm.c[row][colbase]) = acc[n][2 * half + gg];
            }
        }
        __syncthreads();

        // Stream out: one full 256-pos row per wave-instruction (1024 B).
#pragma unroll
        for (int rr = 0; rr < 8; ++rr) {
            const int rloc = 8 * wid + rr;               // 0..31
            const int f    = 32 * half + rloc;           // filter index
            const int np   = n0 + 4 * lane;
            const size_t o = (size_t)(b * NF + f) * LOUT + np;
            f32x4 v = *reinterpret_cast<const f32x4*>(&sm.c[rloc][4 * lane]);
            if (np + 3 < LOUT && (long)(o + 3) < out_elems) {
                *reinterpret_cast<f32x4u*>(out + o) = v;
            } else {
#pragma unroll
                for (int r = 0; r < 4; ++r)
                    if (np + r < LOUT && (long)(o + r) < out_elems)
                        out[o + r] = v[r];
            }
        }
        if (half == 0) __syncthreads();   // before next scatter clobbers sm.c
    }
}

// Complex fallback (folded fp32) in case d_out is interleaved complex.
__global__ __launch_bounds__(256) void gabor_conv_cplx(const float* __restrict__ x,
                                                       float* __restrict__ out,
                                                       long out_elems) {
    __shared__ float sx[256 + KT];
    const int tile = blockIdx.x, g = blockIdx.y, b = blockIdx.z;
    const int t0 = tile * 256, tid = threadIdx.x;
    const float* __restrict__ xb = x + (size_t)b * LIN;
    for (int i = tid; i < 256 + KT - 1; i += 256) {
        int idx = t0 + i;
        sx[i] = (idx < LIN) ? xb[idx] : 0.0f;
    }
    __syncthreads();
    const float* fre = g_filt + g * 16;
    const float* fim = g_filt + KT * NF + g * 16;
    float accre[16], accim[16];
    {
        float x0 = sx[tid], xm = sx[tid + 201];
        const float* c0 = fre;
        const float* cm = fre + 201 * NF;
#pragma unroll
        for (int j = 0; j < 16; ++j) accre[j] = __builtin_fmaf(xm, cm[j], x0 * c0[j]);
#pragma unroll
        for (int j = 0; j < 16; ++j) accim[j] = x0 * fim[j];
    }
#pragma unroll 2
    for (int p = 1; p <= 200; ++p) {
        float x1 = sx[tid + p], x2 = sx[tid + 402 - p];
        float xs = x1 + x2, xd = x1 - x2;
        const float* cr = fre + p * NF;
        const float* ci = fim + p * NF;
#pragma unroll
        for (int j = 0; j < 16; ++j) accre[j] = __builtin_fmaf(xs, cr[j], accre[j]);
#pragma unroll
        for (int j = 0; j < 16; ++j) accim[j] = __builtin_fmaf(xd, ci[j], accim[j]);
    }
    const int t = t0 + tid;
    if (t < LOUT) {
#pragma unroll
        for (int j = 0; j < 16; ++j) {
            size_t o = ((size_t)(b * NF + g * 16 + j) * LOUT + t) * 2;
            if ((long)(o + 1) < out_elems) {
                float2 v; v.x = accre[j]; v.y = accim[j];
                *reinterpret_cast<float2*>(out + o) = v;
            }
        }
    }
}

extern "C" void kernel_launch(void* const* d_in, const int* in_sizes, int n_in,
                              void* d_out, int out_size, void* d_ws, size_t ws_size,
                              hipStream_t stream) {
    const float* x  = (const float*)d_in[0];
    const float* cf = (const float*)d_in[1];
    const float* bw = (const float*)d_in[2];
    float* out = (float*)d_out;
    (void)d_ws; (void)ws_size;

    {
        int n = NF * KP;
        gabor_build_filters<<<(n + 255) / 256, 256, 0, stream>>>(cf, bw);
    }

    const long n_complex = (long)NB * NF * LOUT;
    const bool cplx = ((long)out_size >= 2 * n_complex);

    if (cplx) {
        dim3 grid((LOUT + 255) / 256, NF / 16, NB);
        gabor_conv_cplx<<<grid, 256, 0, stream>>>(x, out, (long)out_size);
    } else {
        dim3 grid((LOUT + NT - 1) / NT, NB);   // (61, 16)
        gabor_conv_mfma<<<grid, TT, 0, stream>>>(x, out, (long)out_size);
    }
}

// Round 19
// 26.355 us; speedup vs baseline: 1.5968x; 1.0386x over previous
//
#include <hip/hip_runtime.h>
#include <math.h>

#define NF    64      // filters
#define KT    402     // taps: arange(-201, 201)
#define KP    416     // padded taps = 13 * 32
#define NSTEP 13      // K-steps of 32
#define NS1   7       // steps in first half (s = 0..6)
#define NS2   6       // steps in second half (s = 7..12)
#define LIN   16000
#define LOUT  15599   // LIN - KT + 1
#define NB    16
#define NT    256     // output positions per block (16 subtiles x 16)
#define SPAN  672     // NT + KP data span per block
#define NCHUNK 84     // SPAN / 8 staging chunks
#define SROW  680     // A copy-row stride (elems)
#define CPAD  260     // C-tile row stride (dwords); 260 mod 32 = 4
#define TT    256     // 4 waves per block

typedef __attribute__((ext_vector_type(8))) _Float16 half8;  // MFMA f16 operand
typedef __attribute__((ext_vector_type(4))) float f32x4;     // MFMA acc
typedef __attribute__((ext_vector_type(4), aligned(4))) float f32x4u;

// fp32 planes [plane][k][f] for the complex fallback path.
__device__ float g_filt[2 * KT * NF];
// Single fp16 B plane, MFMA fragment order: [group][s][lane][j] =
// fp16(coef(filter = 16*group + (lane&15), tap = 8*(lane>>4) + 32*s + j)).
// Each [group][s] slice is 1 KB contiguous -> one gll16 per wave.
__device__ __align__(16) short g_cbh[4][NSTEP][64][8];

__device__ __forceinline__ short f2h(float v) {
    _Float16 h = (_Float16)v;               // v_cvt_f16_f32 (RNE)
    union { _Float16 h; short s; } u; u.h = h;
    return u.s;
}
// Async global->LDS 16B: per-lane global src, wave-uniform LDS base (+lane*16).
__device__ __forceinline__ void gll16(const void* g, void* l) {
    __builtin_amdgcn_global_load_lds(
        (const __attribute__((address_space(1))) void*)g,
        (__attribute__((address_space(3))) void*)l, 16, 0, 0);
}

__global__ void gabor_build_filters(const float* __restrict__ cf,
                                    const float* __restrict__ bw) {
    int idx = blockIdx.x * blockDim.x + threadIdx.x;    // f*KP + k
    if (idx >= NF * KP) return;
    int f = idx / KP;
    int k = idx - f * KP;
    float cre = 0.0f;
    if (k < KT) {
        float t = (float)(k - 201);
        float b = bw[f];
        float env = expf(-(t * t) / (2.0f * b * b)) / (sqrtf(2.0f * (float)M_PI) * b);
        float s, c;
        sincosf(cf[f] * t, &s, &c);
        cre = env * c;
        g_filt[k * NF + f]           = cre;      // re plane (fallback)
        g_filt[KT * NF + k * NF + f] = env * s;  // im plane (fallback)
    }
    int g = f >> 4;
    int s = k >> 5;
    int q = (k >> 3) & 3;
    int j = k & 7;
    int l = (f & 15) | (q << 4);
    g_cbh[g][s][l][j] = f2h(cre);
}

// MFMA implicit GEMM, real part only, fp16 1-term (out = fp16(x)*fp16(c);
// error floor is the shared fp32 filter-build ULP noise -- absmax identical
// across 3 precision schemes, R18 evidence).
// R19 change: B staged in TWO halves (s=0..6, then 7..12 re-staged into the
// same LDS region after a mid-kernel barrier) -> LDS 64.1 -> 38.6 KB ->
// 4 blocks/CU (was 2). All 976 blocks co-resident in ONE generation, and 4
// staggered blocks/CU interleave epilogue write-bursts with other blocks'
// K-loops (R18 post-mortem: 2 aligned blocks/CU left write bursts and MFMA
// serialized; floors MFMA 6.4 + writes 10.2 + LDS 6 want overlap).
// Whole-half-B-in-LDS, barrier-free within each half; A (Hankel of x) via
// 8 shifted fp16 copies, one aligned ds_read_b128 per fragment.
__global__ __launch_bounds__(TT, 4) void gabor_conv_mfma(const float* __restrict__ x,
                                                         float* __restrict__ out,
                                                         long out_elems) {
    __shared__ __align__(16) union {
        struct {
            short h[8][SROW];              // 10,880 B  (xh shifted copies)
            short bh[NS1][4][64][8];       // 28,672 B  (one B half)
        } k;                               // 39,552 B
        float c[32][CPAD];                 // 33,280 B (half C-tile)
    } sm;

    const int tile = blockIdx.x;
    const int b    = blockIdx.y;
    const int n0   = tile * NT;
    const int tid  = threadIdx.x;
    const int wid  = tid >> 6;      // 0..3
    const int lane = tid & 63;

    // Stage B half 1: wave w covers group w, steps 0..6 (1 KB each).
#pragma unroll
    for (int s = 0; s < NS1; ++s)
        gll16(&g_cbh[wid][s][lane][0], &sm.k.bh[s][wid][0][0]);

    // ---- Vectorized A staging: thread j < 84 owns x elements [8j, 8j+16),
    // builds all 8 shifted fp16 windows in registers, writes 8 ds_write_b128.
    if (tid < NCHUNK) {
        const int j  = tid;
        const int e0 = 8 * j;
        const float* __restrict__ src = x + (size_t)b * LIN + n0 + e0;

        float xv[16];
        if (n0 + e0 + 16 <= LIN) {
#pragma unroll
            for (int q = 0; q < 4; ++q) {
                float4 v = *reinterpret_cast<const float4*>(src + 4 * q);
                xv[4 * q + 0] = v.x; xv[4 * q + 1] = v.y;
                xv[4 * q + 2] = v.z; xv[4 * q + 3] = v.w;
            }
        } else {
#pragma unroll
            for (int i = 0; i < 16; ++i) {
                int gi = n0 + e0 + i;
                xv[i] = (gi < LIN) ? src[i] : 0.0f;
            }
        }

        unsigned hd[8];          // packed fp16 pairs (low16 = even elem)
#pragma unroll
        for (int i = 0; i < 8; ++i) {
            unsigned h0 = (unsigned short)f2h(xv[2 * i]);
            unsigned h1 = (unsigned short)f2h(xv[2 * i + 1]);
            hd[i] = h0 | (h1 << 16);
        }

#pragma unroll
        for (int c = 0; c < 8; ++c) {
            unsigned wh[4];
            if ((c & 1) == 0) {
#pragma unroll
                for (int i = 0; i < 4; ++i) wh[i] = hd[c / 2 + i];
            } else {
#pragma unroll
                for (int i = 0; i < 4; ++i) {
                    int k2 = (c - 1) / 2 + i;
                    wh[i] = (hd[k2] >> 16) | (hd[k2 + 1] << 16);   // v_alignbit
                }
            }
            uint4 vh = {wh[0], wh[1], wh[2], wh[3]};
            *reinterpret_cast<uint4*>(&sm.k.h[c][e0]) = vh;
        }
    }
    __syncthreads();    // drains A ds_writes + B half-1 gll16 stages

    // ---- K-loop
    const int c8    = lane & 7;
    const int abase = 8 * ((lane >> 3) & 1) + 8 * (lane >> 4);
    const int subbase = wid * 4;    // this wave's first position-subtile
    const short* ah_base = &sm.k.h[c8][abase + 16 * subbase];

    f32x4 acc[4][4];                // [n][group], all-static indexing
#pragma unroll
    for (int n = 0; n < 4; ++n)
#pragma unroll
        for (int g = 0; g < 4; ++g) {
            f32x4 z = {0.0f, 0.0f, 0.0f, 0.0f};
            acc[n][g] = z;
        }

    // Half 1: s = 0..6, barrier-free.
#pragma unroll
    for (int s = 0; s < NS1; ++s) {
        half8 bh[4];
#pragma unroll
        for (int g = 0; g < 4; ++g)
            bh[g] = *reinterpret_cast<const half8*>(&sm.k.bh[s][g][lane][0]);
#pragma unroll
        for (int n = 0; n < 4; ++n) {
            half8 ah = *reinterpret_cast<const half8*>(ah_base + 16 * n + 32 * s);
#pragma unroll
            for (int g = 0; g < 4; ++g)
                acc[n][g] = __builtin_amdgcn_mfma_f32_16x16x32_f16(ah, bh[g], acc[n][g], 0, 0, 0);
        }
    }

    // Re-stage B half 2 (s = 7..12) into the same region.
    __syncthreads();    // all waves done reading half-1 B
#pragma unroll
    for (int s = 0; s < NS2; ++s)
        gll16(&g_cbh[wid][NS1 + s][lane][0], &sm.k.bh[s][wid][0][0]);
    __syncthreads();    // half-2 stages landed (vmcnt drained by barrier)

    // Half 2: s = 7..12, barrier-free.
#pragma unroll
    for (int s2 = 0; s2 < NS2; ++s2) {
        const int s = NS1 + s2;
        half8 bh[4];
#pragma unroll
        for (int g = 0; g < 4; ++g)
            bh[g] = *reinterpret_cast<const half8*>(&sm.k.bh[s2][g][lane][0]);
#pragma unroll
        for (int n = 0; n < 4; ++n) {
            half8 ah = *reinterpret_cast<const half8*>(ah_base + 16 * n + 32 * s);
#pragma unroll
            for (int g = 0; g < 4; ++g)
                acc[n][g] = __builtin_amdgcn_mfma_f32_16x16x32_f16(ah, bh[g], acc[n][g], 0, 0, 0);
        }
    }

    // ---- Epilogue: two half-tile LDS-transpose passes -> coalesced stores.
    __syncthreads();    // all reads of sm.k done before scatter clobbers union

#pragma unroll
    for (int half = 0; half < 2; ++half) {
#pragma unroll
        for (int n = 0; n < 4; ++n) {
            const int colbase = 16 * (subbase + n) + 4 * (lane >> 4);
#pragma unroll
            for (int gg = 0; gg < 2; ++gg) {
                const int row = 16 * gg + (lane & 15);   // row within half-tile
                *reinterpret_cast<f32x4*>(&sm.c[row][colbase]) = acc[n][2 * half + gg];
            }
        }
        __syncthreads();

        // Stream out: one full 256-pos row per wave-instruction (1024 B).
#pragma unroll
        for (int rr = 0; rr < 8; ++rr) {
            const int rloc = 8 * wid + rr;               // 0..31
            const int f    = 32 * half + rloc;           // filter index
            const int np   = n0 + 4 * lane;
            const size_t o = (size_t)(b * NF + f) * LOUT + np;
            f32x4 v = *reinterpret_cast<const f32x4*>(&sm.c[rloc][4 * lane]);
            if (np + 3 < LOUT && (long)(o + 3) < out_elems) {
                *reinterpret_cast<f32x4u*>(out + o) = v;
            } else {
#pragma unroll
                for (int r = 0; r < 4; ++r)
                    if (np + r < LOUT && (long)(o + r) < out_elems)
                        out[o + r] = v[r];
            }
        }
        if (half == 0) __syncthreads();   // before next scatter clobbers sm.c
    }
}

// Complex fallback (folded fp32) in case d_out is interleaved complex.
__global__ __launch_bounds__(256) void gabor_conv_cplx(const float* __restrict__ x,
                                                       float* __restrict__ out,
                                                       long out_elems) {
    __shared__ float sx[256 + KT];
    const int tile = blockIdx.x, g = blockIdx.y, b = blockIdx.z;
    const int t0 = tile * 256, tid = threadIdx.x;
    const float* __restrict__ xb = x + (size_t)b * LIN;
    for (int i = tid; i < 256 + KT - 1; i += 256) {
        int idx = t0 + i;
        sx[i] = (idx < LIN) ? xb[idx] : 0.0f;
    }
    __syncthreads();
    const float* fre = g_filt + g * 16;
    const float* fim = g_filt + KT * NF + g * 16;
    float accre[16], accim[16];
    {
        float x0 = sx[tid], xm = sx[tid + 201];
        const float* c0 = fre;
        const float* cm = fre + 201 * NF;
#pragma unroll
        for (int j = 0; j < 16; ++j) accre[j] = __builtin_fmaf(xm, cm[j], x0 * c0[j]);
#pragma unroll
        for (int j = 0; j < 16; ++j) accim[j] = x0 * fim[j];
    }
#pragma unroll 2
    for (int p = 1; p <= 200; ++p) {
        float x1 = sx[tid + p], x2 = sx[tid + 402 - p];
        float xs = x1 + x2, xd = x1 - x2;
        const float* cr = fre + p * NF;
        const float* ci = fim + p * NF;
#pragma unroll
        for (int j = 0; j < 16; ++j) accre[j] = __builtin_fmaf(xs, cr[j], accre[j]);
#pragma unroll
        for (int j = 0; j < 16; ++j) accim[j] = __builtin_fmaf(xd, ci[j], accim[j]);
    }
    const int t = t0 + tid;
    if (t < LOUT) {
#pragma unroll
        for (int j = 0; j < 16; ++j) {
            size_t o = ((size_t)(b * NF + g * 16 + j) * LOUT + t) * 2;
            if ((long)(o + 1) < out_elems) {
                float2 v; v.x = accre[j]; v.y = accim[j];
                *reinterpret_cast<float2*>(out + o) = v;
            }
        }
    }
}

extern "C" void kernel_launch(void* const* d_in, const int* in_sizes, int n_in,
                              void* d_out, int out_size, void* d_ws, size_t ws_size,
                              hipStream_t stream) {
    const float* x  = (const float*)d_in[0];
    const float* cf = (const float*)d_in[1];
    const float* bw = (const float*)d_in[2];
    float* out = (float*)d_out;
    (void)d_ws; (void)ws_size;

    {
        int n = NF * KP;
        gabor_build_filters<<<(n + 255) / 256, 256, 0, stream>>>(cf, bw);
    }

    const long n_complex = (long)NB * NF * LOUT;
    const bool cplx = ((long)out_size >= 2 * n_complex);

    if (cplx) {
        dim3 grid((LOUT + 255) / 256, NF / 16, NB);
        gabor_conv_cplx<<<grid, 256, 0, stream>>>(x, out, (long)out_size);
    } else {
        dim3 grid((LOUT + NT - 1) / NT, NB);   // (61, 16)
        gabor_conv_mfma<<<grid, TT, 0, stream>>>(x, out, (long)out_size);
    }
}